// Round 18
// baseline (541.077 us; speedup 1.0000x reference)
//
#include <hip/hip_runtime.h>
#include <hip/hip_bf16.h>

#define TQ_D   1024
#define TQ_KC  16
#define MERGE_K 512          // OpenBLAS KC-panel boundary (proven R9)
#define TQ_TOL  1.0e-3f      // >= 2x worst-case |y_mfma - y_ref| bound
#define TQ_FLAG 32.0f        // in-band suspect flag added to index

typedef __attribute__((ext_vector_type(8))) short bf16x8;
typedef __attribute__((ext_vector_type(4))) float f32x4;

__device__ __forceinline__ unsigned short f2bf(float f) {
    union { __hip_bfloat16 h; unsigned short s; } u;
    u.h = __float2bfloat16(f);
    return u.s;
}
__device__ __forceinline__ float bf2f(unsigned short s) {
    union { unsigned int u; float f; } v;
    v.u = (unsigned int)s << 16;
    return v.f;
}

// ---------------------------------------------------------------------------
// K1-MFMA: y = x @ Pi^T via bf16 hi/lo 3-term split (xh*ph + xl*ph + xh*pl),
// f32 MFMA accum. Epilogue: literal f32 argmin; elements within TOL of any
// decision midpoint get flagged (idx+32) for exact recompute.
// Structure cloned from the proven tq_dq_mfma (R15): 128x128 tile, BK=32,
// 4 waves 2x2, fragments single ds_read_b128, C/D map col=lane&15,
// row=(lane>>4)*4+reg. B-staging is straight Pi row copy (y needs Pi^T, so
// B[n][k] = Pi[n][k] -- same layout as A).
// ---------------------------------------------------------------------------
__global__ __launch_bounds__(256)
void tq_rq_mfma(const float* __restrict__ X,
                const float* __restrict__ Pi,
                const float* __restrict__ Cent,
                float* __restrict__ OutIdx)
{
    __shared__ unsigned short Xh[128][40];
    __shared__ unsigned short Xl[128][40];
    __shared__ unsigned short Ph[128][40];
    __shared__ unsigned short Pl[128][40];

    const int tid  = threadIdx.x;
    const int lane = tid & 63;
    const int wv   = tid >> 6;
    const int m0 = blockIdx.y * 128;
    const int n0 = blockIdx.x * 128;
    const int wr = (wv >> 1) * 64;
    const int wc = (wv & 1) * 64;
    const int l15 = lane & 15;
    const int k8  = (lane >> 4) * 8;

    // staging: each thread stages 16 A-floats and 16 B-floats per tile
    const int srow = tid >> 1;             // 0..127
    const int scol = (tid & 1) * 16;       // 0 or 16

    const float* aP = X  + (size_t)(m0 + srow) * TQ_D + scol;
    const float* bP = Pi + (size_t)(n0 + srow) * TQ_D + scol;

    f32x4 acc[4][4];
#pragma unroll
    for (int i = 0; i < 4; ++i)
#pragma unroll
        for (int j = 0; j < 4; ++j)
#pragma unroll
            for (int r = 0; r < 4; ++r) acc[i][j][r] = 0.0f;

    float4 va[4], vb[4];
#pragma unroll
    for (int q = 0; q < 4; ++q) {
        va[q] = *(const float4*)(aP + 4 * q);
        vb[q] = *(const float4*)(bP + 4 * q);
    }

    // stage tile 0 (hi/lo split; x - bf2f(h) is exact by Sterbenz)
#pragma unroll
    for (int q = 0; q < 4; ++q) {
        ushort4 ah, al, bh, bl;
        const float* fa = (const float*)&va[q];
        const float* fb = (const float*)&vb[q];
        ah.x = f2bf(fa[0]); al.x = f2bf(fa[0] - bf2f(ah.x));
        ah.y = f2bf(fa[1]); al.y = f2bf(fa[1] - bf2f(ah.y));
        ah.z = f2bf(fa[2]); al.z = f2bf(fa[2] - bf2f(ah.z));
        ah.w = f2bf(fa[3]); al.w = f2bf(fa[3] - bf2f(ah.w));
        bh.x = f2bf(fb[0]); bl.x = f2bf(fb[0] - bf2f(bh.x));
        bh.y = f2bf(fb[1]); bl.y = f2bf(fb[1] - bf2f(bh.y));
        bh.z = f2bf(fb[2]); bl.z = f2bf(fb[2] - bf2f(bh.z));
        bh.w = f2bf(fb[3]); bl.w = f2bf(fb[3] - bf2f(bh.w));
        *(ushort4*)&Xh[srow][scol + 4 * q] = ah;
        *(ushort4*)&Xl[srow][scol + 4 * q] = al;
        *(ushort4*)&Ph[srow][scol + 4 * q] = bh;
        *(ushort4*)&Pl[srow][scol + 4 * q] = bl;
    }
    __syncthreads();

    for (int kt = 0; kt < 32; ++kt) {
        const bool more = (kt + 1) < 32;
        if (more) {
            const float* ap = aP + (kt + 1) * 32;
            const float* bp = bP + (kt + 1) * 32;
#pragma unroll
            for (int q = 0; q < 4; ++q) {
                va[q] = *(const float4*)(ap + 4 * q);
                vb[q] = *(const float4*)(bp + 4 * q);
            }
        }

        bf16x8 afh[4], afl[4], bfh[4], bfl[4];
#pragma unroll
        for (int i = 0; i < 4; ++i) {
            afh[i] = *(const bf16x8*)&Xh[wr + i * 16 + l15][k8];
            afl[i] = *(const bf16x8*)&Xl[wr + i * 16 + l15][k8];
        }
#pragma unroll
        for (int j = 0; j < 4; ++j) {
            bfh[j] = *(const bf16x8*)&Ph[wc + j * 16 + l15][k8];
            bfl[j] = *(const bf16x8*)&Pl[wc + j * 16 + l15][k8];
        }

#pragma unroll
        for (int i = 0; i < 4; ++i)
#pragma unroll
            for (int j = 0; j < 4; ++j) {
                acc[i][j] = __builtin_amdgcn_mfma_f32_16x16x32_bf16(
                    afh[i], bfh[j], acc[i][j], 0, 0, 0);
                acc[i][j] = __builtin_amdgcn_mfma_f32_16x16x32_bf16(
                    afl[i], bfh[j], acc[i][j], 0, 0, 0);
                acc[i][j] = __builtin_amdgcn_mfma_f32_16x16x32_bf16(
                    afh[i], bfl[j], acc[i][j], 0, 0, 0);
            }

        if (more) {
            __syncthreads();
#pragma unroll
            for (int q = 0; q < 4; ++q) {
                ushort4 ah, al, bh, bl;
                const float* fa = (const float*)&va[q];
                const float* fb = (const float*)&vb[q];
                ah.x = f2bf(fa[0]); al.x = f2bf(fa[0] - bf2f(ah.x));
                ah.y = f2bf(fa[1]); al.y = f2bf(fa[1] - bf2f(ah.y));
                ah.z = f2bf(fa[2]); al.z = f2bf(fa[2] - bf2f(ah.z));
                ah.w = f2bf(fa[3]); al.w = f2bf(fa[3] - bf2f(ah.w));
                bh.x = f2bf(fb[0]); bl.x = f2bf(fb[0] - bf2f(bh.x));
                bh.y = f2bf(fb[1]); bl.y = f2bf(fb[1] - bf2f(bh.y));
                bh.z = f2bf(fb[2]); bl.z = f2bf(fb[2] - bf2f(bh.z));
                bh.w = f2bf(fb[3]); bl.w = f2bf(fb[3] - bf2f(bh.w));
                *(ushort4*)&Xh[srow][scol + 4 * q] = ah;
                *(ushort4*)&Xl[srow][scol + 4 * q] = al;
                *(ushort4*)&Ph[srow][scol + 4 * q] = bh;
                *(ushort4*)&Pl[srow][scol + 4 * q] = bl;
            }
            __syncthreads();
        }
    }

    // epilogue: literal f32 argmin + boundary-proximity flag
    float c[TQ_KC];
#pragma unroll
    for (int q = 0; q < TQ_KC; ++q) c[q] = Cent[q];

#pragma unroll
    for (int i = 0; i < 4; ++i)
#pragma unroll
        for (int j = 0; j < 4; ++j)
#pragma unroll
            for (int r = 0; r < 4; ++r) {
                const int row = wr + i * 16 + (lane >> 4) * 4 + r;
                const int col = wc + j * 16 + l15;
                const float y = acc[i][j][r];
                int best = 0;
                float bd = fabsf(y - c[0]);
#pragma unroll
                for (int q = 1; q < TQ_KC; ++q) {
                    const float d = fabsf(y - c[q]);
                    if (d < bd) { bd = d; best = q; }
                }
                float dist = 1e30f;
#pragma unroll
                for (int q = 0; q < TQ_KC - 1; ++q) {
                    const float mid = 0.5f * (c[q] + c[q + 1]);
                    dist = fminf(dist, fabsf(y - mid));
                }
                OutIdx[(size_t)(m0 + row) * TQ_D + n0 + col] =
                    (float)best + ((dist < TQ_TOL) ? TQ_FLAG : 0.0f);
            }
}

// ---------------------------------------------------------------------------
// Fixup: flagged elements get the EXACT reference realization — serial
// ascending-k f32 FMA chains within KC=512 panels, one f32 merge add,
// literal f32 argmin. One thread per element.
// ---------------------------------------------------------------------------
__global__ __launch_bounds__(256)
void tq_fixup(const float* __restrict__ X,
              const float* __restrict__ Pi,
              const float* __restrict__ Cent,
              float* __restrict__ OutIdx,
              int total)
{
    const int e = blockIdx.x * 256 + threadIdx.x;
    if (e >= total) return;
    const float v = OutIdx[e];
    if (v < TQ_FLAG - 0.5f) return;   // not flagged

    const int m = e >> 10;            // TQ_D = 1024
    const int n = e & (TQ_D - 1);
    const float* xr = X  + (size_t)m * TQ_D;
    const float* pr = Pi + (size_t)n * TQ_D;

    float a1 = 0.0f, a2 = 0.0f;
    for (int k = 0; k < MERGE_K; ++k)        a1 = fmaf(xr[k], pr[k], a1);
    for (int k = MERGE_K; k < TQ_D; ++k)     a2 = fmaf(xr[k], pr[k], a2);
    const float y = a1 + a2;                 // exact R9 panel merge

    float c[TQ_KC];
#pragma unroll
    for (int q = 0; q < TQ_KC; ++q) c[q] = Cent[q];
    int best = 0;
    float bd = fabsf(y - c[0]);
#pragma unroll
    for (int q = 1; q < TQ_KC; ++q) {
        const float d = fabsf(y - c[q]);
        if (d < bd) { bd = d; best = q; }
    }
    OutIdx[e] = (float)best;
}

// ---------------------------------------------------------------------------
// Kernel 2 (MFMA, proven R15): x_hat = dequant(idx) @ Pi, bf16 MFMA f32-acc.
// ---------------------------------------------------------------------------
__global__ __launch_bounds__(256)
void tq_dq_mfma(const float* __restrict__ IdxF,
                const float* __restrict__ Pi,
                const float* __restrict__ Cent,
                float* __restrict__ Xhat)
{
    __shared__ unsigned short Ys[128][40];
    __shared__ unsigned short Ps[128][40];
    __shared__ unsigned short csb[TQ_KC];

    const int tid  = threadIdx.x;
    const int lane = tid & 63;
    const int wv   = tid >> 6;
    const int m0 = blockIdx.y * 128;
    const int n0 = blockIdx.x * 128;
    const int wr = (wv >> 1) * 64;
    const int wc = (wv & 1) * 64;
    const int l15 = lane & 15;
    const int k8  = (lane >> 4) * 8;

    const int arow = tid >> 1;
    const int acol = (tid & 1) * 16;
    const int bn   = tid & 127;
    const int bkq  = (tid >> 7) * 16;

    const float* aP = IdxF + (size_t)(m0 + arow) * TQ_D + acol;
    const float* bP = Pi + (size_t)bkq * TQ_D + n0 + bn;

    if (tid < TQ_KC) csb[tid] = f2bf(Cent[tid]);

    f32x4 acc[4][4];
#pragma unroll
    for (int i = 0; i < 4; ++i)
#pragma unroll
        for (int j = 0; j < 4; ++j)
#pragma unroll
            for (int r = 0; r < 4; ++r) acc[i][j][r] = 0.0f;

    float4 va[4];
    float  vb[16];
#pragma unroll
    for (int q = 0; q < 4; ++q) va[q] = *(const float4*)(aP + 4 * q);
#pragma unroll
    for (int k = 0; k < 16; ++k) vb[k] = bP[(size_t)k * TQ_D];

    __syncthreads();   // csb ready

#pragma unroll
    for (int q = 0; q < 4; ++q) {
        ushort4 w;
        w.x = csb[(int)va[q].x & 15];
        w.y = csb[(int)va[q].y & 15];
        w.z = csb[(int)va[q].z & 15];
        w.w = csb[(int)va[q].w & 15];
        *(ushort4*)&Ys[arow][acol + 4 * q] = w;
    }
#pragma unroll
    for (int k = 0; k < 16; ++k) Ps[bn][bkq + k] = f2bf(vb[k]);
    __syncthreads();

    for (int kt = 0; kt < 32; ++kt) {
        const bool more = (kt + 1) < 32;
        if (more) {
            const float* ap = aP + (kt + 1) * 32;
            const float* bp = bP + (size_t)(kt + 1) * 32 * TQ_D;
#pragma unroll
            for (int q = 0; q < 4; ++q) va[q] = *(const float4*)(ap + 4 * q);
#pragma unroll
            for (int k = 0; k < 16; ++k) vb[k] = bp[(size_t)k * TQ_D];
        }

        bf16x8 af[4], bfr[4];
#pragma unroll
        for (int i = 0; i < 4; ++i)
            af[i] = *(const bf16x8*)&Ys[wr + i * 16 + l15][k8];
#pragma unroll
        for (int j = 0; j < 4; ++j)
            bfr[j] = *(const bf16x8*)&Ps[wc + j * 16 + l15][k8];

#pragma unroll
        for (int i = 0; i < 4; ++i)
#pragma unroll
            for (int j = 0; j < 4; ++j)
                acc[i][j] = __builtin_amdgcn_mfma_f32_16x16x32_bf16(
                    af[i], bfr[j], acc[i][j], 0, 0, 0);

        if (more) {
            __syncthreads();
#pragma unroll
            for (int q = 0; q < 4; ++q) {
                ushort4 w;
                w.x = csb[(int)va[q].x & 15];
                w.y = csb[(int)va[q].y & 15];
                w.z = csb[(int)va[q].z & 15];
                w.w = csb[(int)va[q].w & 15];
                *(ushort4*)&Ys[arow][acol + 4 * q] = w;
            }
#pragma unroll
            for (int k = 0; k < 16; ++k) Ps[bn][bkq + k] = f2bf(vb[k]);
            __syncthreads();
        }
    }

#pragma unroll
    for (int i = 0; i < 4; ++i)
#pragma unroll
        for (int j = 0; j < 4; ++j)
#pragma unroll
            for (int r = 0; r < 4; ++r) {
                const int row = wr + i * 16 + (lane >> 4) * 4 + r;
                const int col = wc + j * 16 + l15;
                Xhat[(size_t)(m0 + row) * TQ_D + n0 + col] = acc[i][j][r];
            }
}

// ---------------------------------------------------------------------------
extern "C" void kernel_launch(void* const* d_in, const int* in_sizes, int n_in,
                              void* d_out, int out_size, void* d_ws, size_t ws_size,
                              hipStream_t stream)
{
    const float* x    = (const float*)d_in[0];   // [N, 1024]
    const float* Pi   = (const float*)d_in[1];   // [1024, 1024]
    const float* cent = (const float*)d_in[2];   // [16]
    float* out = (float*)d_out;

    const int ND = in_sizes[0];      // N * 1024
    const int N  = ND / TQ_D;        // 4096

    float* xhat = out;               // output 0: [N,1024] f32
    float* oidx = out + ND;          // output 1: indices as float

    dim3 grid(TQ_D / 128, N / 128);  // (8, 32) = 256 blocks

    // Pass 1: MFMA hi/lo-split rotate+quantize (+ suspect flags) -> oidx.
    tq_rq_mfma<<<grid, 256, 0, stream>>>(x, Pi, cent, oidx);

    // Pass 2: exact serial recompute of flagged elements (R9 realization).
    tq_fixup<<<(ND + 255) / 256, 256, 0, stream>>>(x, Pi, cent, oidx, ND);

    // Pass 3: dequant + unrotate (MFMA) -> xhat.
    tq_dq_mfma<<<grid, 256, 0, stream>>>(oidx, Pi, cent, xhat);
}

// Round 19
// 520.288 us; speedup vs baseline: 1.0400x; 1.0400x over previous
//
#include <hip/hip_runtime.h>
#include <hip/hip_bf16.h>

#define TQ_D   1024
#define TQ_KC  16
#define MERGE_K 512          // OpenBLAS KC-panel boundary (proven R9)
#define TQ_TOL  1.0e-3f      // >= 2x worst-case |y_mfma - y_ref| bound

typedef __attribute__((ext_vector_type(8))) short bf16x8;
typedef __attribute__((ext_vector_type(4))) float f32x4;

__device__ __forceinline__ unsigned short f2bf(float f) {
    union { __hip_bfloat16 h; unsigned short s; } u;
    u.h = __float2bfloat16(f);
    return u.s;
}
__device__ __forceinline__ float bf2f(unsigned short s) {
    union { unsigned int u; float f; } v;
    v.u = (unsigned int)s << 16;
    return v.f;
}

// ---------------------------------------------------------------------------
// K1-MFMA (proven R18): y = x @ Pi^T via bf16 hi/lo 3-term split, f32 MFMA
// accum, literal f32 argmin. Writes PLAIN indices; boundary-close elements
// (dist < TOL) are pushed into a compact suspect list via atomicAdd.
// ---------------------------------------------------------------------------
__global__ __launch_bounds__(256)
void tq_rq_mfma(const float* __restrict__ X,
                const float* __restrict__ Pi,
                const float* __restrict__ Cent,
                float* __restrict__ OutIdx,
                unsigned* __restrict__ Counter,
                unsigned* __restrict__ List,
                unsigned cap)
{
    __shared__ unsigned short Xh[128][40];
    __shared__ unsigned short Xl[128][40];
    __shared__ unsigned short Ph[128][40];
    __shared__ unsigned short Pl[128][40];

    const int tid  = threadIdx.x;
    const int lane = tid & 63;
    const int wv   = tid >> 6;
    const int m0 = blockIdx.y * 128;
    const int n0 = blockIdx.x * 128;
    const int wr = (wv >> 1) * 64;
    const int wc = (wv & 1) * 64;
    const int l15 = lane & 15;
    const int k8  = (lane >> 4) * 8;

    const int srow = tid >> 1;
    const int scol = (tid & 1) * 16;

    const float* aP = X  + (size_t)(m0 + srow) * TQ_D + scol;
    const float* bP = Pi + (size_t)(n0 + srow) * TQ_D + scol;

    f32x4 acc[4][4];
#pragma unroll
    for (int i = 0; i < 4; ++i)
#pragma unroll
        for (int j = 0; j < 4; ++j)
#pragma unroll
            for (int r = 0; r < 4; ++r) acc[i][j][r] = 0.0f;

    float4 va[4], vb[4];
#pragma unroll
    for (int q = 0; q < 4; ++q) {
        va[q] = *(const float4*)(aP + 4 * q);
        vb[q] = *(const float4*)(bP + 4 * q);
    }

#pragma unroll
    for (int q = 0; q < 4; ++q) {
        ushort4 ah, al, bh, bl;
        const float* fa = (const float*)&va[q];
        const float* fb = (const float*)&vb[q];
        ah.x = f2bf(fa[0]); al.x = f2bf(fa[0] - bf2f(ah.x));
        ah.y = f2bf(fa[1]); al.y = f2bf(fa[1] - bf2f(ah.y));
        ah.z = f2bf(fa[2]); al.z = f2bf(fa[2] - bf2f(ah.z));
        ah.w = f2bf(fa[3]); al.w = f2bf(fa[3] - bf2f(ah.w));
        bh.x = f2bf(fb[0]); bl.x = f2bf(fb[0] - bf2f(bh.x));
        bh.y = f2bf(fb[1]); bl.y = f2bf(fb[1] - bf2f(bh.y));
        bh.z = f2bf(fb[2]); bl.z = f2bf(fb[2] - bf2f(bh.z));
        bh.w = f2bf(fb[3]); bl.w = f2bf(fb[3] - bf2f(bh.w));
        *(ushort4*)&Xh[srow][scol + 4 * q] = ah;
        *(ushort4*)&Xl[srow][scol + 4 * q] = al;
        *(ushort4*)&Ph[srow][scol + 4 * q] = bh;
        *(ushort4*)&Pl[srow][scol + 4 * q] = bl;
    }
    __syncthreads();

    for (int kt = 0; kt < 32; ++kt) {
        const bool more = (kt + 1) < 32;
        if (more) {
            const float* ap = aP + (kt + 1) * 32;
            const float* bp = bP + (kt + 1) * 32;
#pragma unroll
            for (int q = 0; q < 4; ++q) {
                va[q] = *(const float4*)(ap + 4 * q);
                vb[q] = *(const float4*)(bp + 4 * q);
            }
        }

        bf16x8 afh[4], afl[4], bfh[4], bfl[4];
#pragma unroll
        for (int i = 0; i < 4; ++i) {
            afh[i] = *(const bf16x8*)&Xh[wr + i * 16 + l15][k8];
            afl[i] = *(const bf16x8*)&Xl[wr + i * 16 + l15][k8];
        }
#pragma unroll
        for (int j = 0; j < 4; ++j) {
            bfh[j] = *(const bf16x8*)&Ph[wc + j * 16 + l15][k8];
            bfl[j] = *(const bf16x8*)&Pl[wc + j * 16 + l15][k8];
        }

#pragma unroll
        for (int i = 0; i < 4; ++i)
#pragma unroll
            for (int j = 0; j < 4; ++j) {
                acc[i][j] = __builtin_amdgcn_mfma_f32_16x16x32_bf16(
                    afh[i], bfh[j], acc[i][j], 0, 0, 0);
                acc[i][j] = __builtin_amdgcn_mfma_f32_16x16x32_bf16(
                    afl[i], bfh[j], acc[i][j], 0, 0, 0);
                acc[i][j] = __builtin_amdgcn_mfma_f32_16x16x32_bf16(
                    afh[i], bfl[j], acc[i][j], 0, 0, 0);
            }

        if (more) {
            __syncthreads();
#pragma unroll
            for (int q = 0; q < 4; ++q) {
                ushort4 ah, al, bh, bl;
                const float* fa = (const float*)&va[q];
                const float* fb = (const float*)&vb[q];
                ah.x = f2bf(fa[0]); al.x = f2bf(fa[0] - bf2f(ah.x));
                ah.y = f2bf(fa[1]); al.y = f2bf(fa[1] - bf2f(ah.y));
                ah.z = f2bf(fa[2]); al.z = f2bf(fa[2] - bf2f(ah.z));
                ah.w = f2bf(fa[3]); al.w = f2bf(fa[3] - bf2f(ah.w));
                bh.x = f2bf(fb[0]); bl.x = f2bf(fb[0] - bf2f(bh.x));
                bh.y = f2bf(fb[1]); bl.y = f2bf(fb[1] - bf2f(bh.y));
                bh.z = f2bf(fb[2]); bl.z = f2bf(fb[2] - bf2f(bh.z));
                bh.w = f2bf(fb[3]); bl.w = f2bf(fb[3] - bf2f(bh.w));
                *(ushort4*)&Xh[srow][scol + 4 * q] = ah;
                *(ushort4*)&Xl[srow][scol + 4 * q] = al;
                *(ushort4*)&Ph[srow][scol + 4 * q] = bh;
                *(ushort4*)&Pl[srow][scol + 4 * q] = bl;
            }
            __syncthreads();
        }
    }

    float c[TQ_KC];
#pragma unroll
    for (int q = 0; q < TQ_KC; ++q) c[q] = Cent[q];

#pragma unroll
    for (int i = 0; i < 4; ++i)
#pragma unroll
        for (int j = 0; j < 4; ++j)
#pragma unroll
            for (int r = 0; r < 4; ++r) {
                const int row = m0 + wr + i * 16 + (lane >> 4) * 4 + r;
                const int col = n0 + wc + j * 16 + l15;
                const float y = acc[i][j][r];
                int best = 0;
                float bd = fabsf(y - c[0]);
#pragma unroll
                for (int q = 1; q < TQ_KC; ++q) {
                    const float d = fabsf(y - c[q]);
                    if (d < bd) { bd = d; best = q; }
                }
                float dist = 1e30f;
#pragma unroll
                for (int q = 0; q < TQ_KC - 1; ++q) {
                    const float mid = 0.5f * (c[q] + c[q + 1]);
                    dist = fminf(dist, fabsf(y - mid));
                }
                if (dist < TQ_TOL) {
                    const unsigned slot = atomicAdd(Counter, 1u);
                    if (slot < cap)
                        List[slot] = ((unsigned)row << 10) | (unsigned)col;
                }
                OutIdx[(size_t)row * TQ_D + col] = (float)best;
            }
}

// ---------------------------------------------------------------------------
// Fixup (compact): one thread per suspect-list entry, all lanes dense.
// EXACT reference realization: serial ascending-k f32 FMA chains within
// KC=512 panels (float4 load + 4 in-order fmaf preserves the chain), one
// f32 merge add, literal f32 argmin.
// ---------------------------------------------------------------------------
__global__ __launch_bounds__(256)
void tq_fixup(const float* __restrict__ X,
              const float* __restrict__ Pi,
              const float* __restrict__ Cent,
              float* __restrict__ OutIdx,
              const unsigned* __restrict__ Counter,
              const unsigned* __restrict__ List,
              unsigned cap)
{
    const unsigned count = min(*Counter, cap);
    for (unsigned s = blockIdx.x * 256 + threadIdx.x; s < count;
         s += gridDim.x * 256) {
        const unsigned id = List[s];
        const int m = id >> 10;
        const int n = id & (TQ_D - 1);
        const float* xr = X  + (size_t)m * TQ_D;
        const float* pr = Pi + (size_t)n * TQ_D;

        float a1 = 0.0f, a2 = 0.0f;
        for (int k = 0; k < MERGE_K; k += 4) {
            const float4 xa = *(const float4*)(xr + k);
            const float4 pa = *(const float4*)(pr + k);
            a1 = fmaf(xa.x, pa.x, a1);
            a1 = fmaf(xa.y, pa.y, a1);
            a1 = fmaf(xa.z, pa.z, a1);
            a1 = fmaf(xa.w, pa.w, a1);
        }
        for (int k = MERGE_K; k < TQ_D; k += 4) {
            const float4 xa = *(const float4*)(xr + k);
            const float4 pa = *(const float4*)(pr + k);
            a2 = fmaf(xa.x, pa.x, a2);
            a2 = fmaf(xa.y, pa.y, a2);
            a2 = fmaf(xa.z, pa.z, a2);
            a2 = fmaf(xa.w, pa.w, a2);
        }
        const float y = a1 + a2;   // exact R9 panel merge

        float c[TQ_KC];
#pragma unroll
        for (int q = 0; q < TQ_KC; ++q) c[q] = Cent[q];
        int best = 0;
        float bd = fabsf(y - c[0]);
#pragma unroll
        for (int q = 1; q < TQ_KC; ++q) {
            const float d = fabsf(y - c[q]);
            if (d < bd) { bd = d; best = q; }
        }
        OutIdx[(size_t)m * TQ_D + n] = (float)best;
    }
}

// ---------------------------------------------------------------------------
// Kernel 2 (MFMA, proven R15): x_hat = dequant(idx) @ Pi, bf16 MFMA f32-acc.
// Overwrites the counter/list scratch (xhat region) with the real output.
// ---------------------------------------------------------------------------
__global__ __launch_bounds__(256)
void tq_dq_mfma(const float* __restrict__ IdxF,
                const float* __restrict__ Pi,
                const float* __restrict__ Cent,
                float* __restrict__ Xhat)
{
    __shared__ unsigned short Ys[128][40];
    __shared__ unsigned short Ps[128][40];
    __shared__ unsigned short csb[TQ_KC];

    const int tid  = threadIdx.x;
    const int lane = tid & 63;
    const int wv   = tid >> 6;
    const int m0 = blockIdx.y * 128;
    const int n0 = blockIdx.x * 128;
    const int wr = (wv >> 1) * 64;
    const int wc = (wv & 1) * 64;
    const int l15 = lane & 15;
    const int k8  = (lane >> 4) * 8;

    const int arow = tid >> 1;
    const int acol = (tid & 1) * 16;
    const int bn   = tid & 127;
    const int bkq  = (tid >> 7) * 16;

    const float* aP = IdxF + (size_t)(m0 + arow) * TQ_D + acol;
    const float* bP = Pi + (size_t)bkq * TQ_D + n0 + bn;

    if (tid < TQ_KC) csb[tid] = f2bf(Cent[tid]);

    f32x4 acc[4][4];
#pragma unroll
    for (int i = 0; i < 4; ++i)
#pragma unroll
        for (int j = 0; j < 4; ++j)
#pragma unroll
            for (int r = 0; r < 4; ++r) acc[i][j][r] = 0.0f;

    float4 va[4];
    float  vb[16];
#pragma unroll
    for (int q = 0; q < 4; ++q) va[q] = *(const float4*)(aP + 4 * q);
#pragma unroll
    for (int k = 0; k < 16; ++k) vb[k] = bP[(size_t)k * TQ_D];

    __syncthreads();   // csb ready

#pragma unroll
    for (int q = 0; q < 4; ++q) {
        ushort4 w;
        w.x = csb[(int)va[q].x & 15];
        w.y = csb[(int)va[q].y & 15];
        w.z = csb[(int)va[q].z & 15];
        w.w = csb[(int)va[q].w & 15];
        *(ushort4*)&Ys[arow][acol + 4 * q] = w;
    }
#pragma unroll
    for (int k = 0; k < 16; ++k) Ps[bn][bkq + k] = f2bf(vb[k]);
    __syncthreads();

    for (int kt = 0; kt < 32; ++kt) {
        const bool more = (kt + 1) < 32;
        if (more) {
            const float* ap = aP + (kt + 1) * 32;
            const float* bp = bP + (size_t)(kt + 1) * 32 * TQ_D;
#pragma unroll
            for (int q = 0; q < 4; ++q) va[q] = *(const float4*)(ap + 4 * q);
#pragma unroll
            for (int k = 0; k < 16; ++k) vb[k] = bp[(size_t)k * TQ_D];
        }

        bf16x8 af[4], bfr[4];
#pragma unroll
        for (int i = 0; i < 4; ++i)
            af[i] = *(const bf16x8*)&Ys[wr + i * 16 + l15][k8];
#pragma unroll
        for (int j = 0; j < 4; ++j)
            bfr[j] = *(const bf16x8*)&Ps[wc + j * 16 + l15][k8];

#pragma unroll
        for (int i = 0; i < 4; ++i)
#pragma unroll
            for (int j = 0; j < 4; ++j)
                acc[i][j] = __builtin_amdgcn_mfma_f32_16x16x32_bf16(
                    af[i], bfr[j], acc[i][j], 0, 0, 0);

        if (more) {
            __syncthreads();
#pragma unroll
            for (int q = 0; q < 4; ++q) {
                ushort4 w;
                w.x = csb[(int)va[q].x & 15];
                w.y = csb[(int)va[q].y & 15];
                w.z = csb[(int)va[q].z & 15];
                w.w = csb[(int)va[q].w & 15];
                *(ushort4*)&Ys[arow][acol + 4 * q] = w;
            }
#pragma unroll
            for (int k = 0; k < 16; ++k) Ps[bn][bkq + k] = f2bf(vb[k]);
            __syncthreads();
        }
    }

#pragma unroll
    for (int i = 0; i < 4; ++i)
#pragma unroll
        for (int j = 0; j < 4; ++j)
#pragma unroll
            for (int r = 0; r < 4; ++r) {
                const int row = wr + i * 16 + (lane >> 4) * 4 + r;
                const int col = wc + j * 16 + l15;
                Xhat[(size_t)(m0 + row) * TQ_D + n0 + col] = acc[i][j][r];
            }
}

// ---------------------------------------------------------------------------
extern "C" void kernel_launch(void* const* d_in, const int* in_sizes, int n_in,
                              void* d_out, int out_size, void* d_ws, size_t ws_size,
                              hipStream_t stream)
{
    const float* x    = (const float*)d_in[0];   // [N, 1024]
    const float* Pi   = (const float*)d_in[1];   // [1024, 1024]
    const float* cent = (const float*)d_in[2];   // [16]
    float* out = (float*)d_out;

    const int ND = in_sizes[0];      // N * 1024
    const int N  = ND / TQ_D;        // 4096

    float* xhat = out;               // output 0 (scratch: counter+list pre-K2)
    float* oidx = out + ND;          // output 1: indices as float

    unsigned* counter = (unsigned*)xhat;
    unsigned* list    = (unsigned*)xhat + 16;
    const unsigned cap = (unsigned)(ND - 16);

    hipMemsetAsync(counter, 0, 4, stream);   // zero suspect counter

    dim3 grid(TQ_D / 128, N / 128);  // (8, 32) = 256 blocks

    // Pass 1: MFMA hi/lo rotate+quantize -> plain indices + compact suspects.
    tq_rq_mfma<<<grid, 256, 0, stream>>>(x, Pi, cent, oidx, counter, list, cap);

    // Pass 2: dense exact recompute of suspects (R9 realization).
    tq_fixup<<<256, 256, 0, stream>>>(x, Pi, cent, oidx, counter, list, cap);

    // Pass 3: dequant + unrotate (MFMA) -> xhat (overwrites scratch).
    tq_dq_mfma<<<grid, 256, 0, stream>>>(oidx, Pi, cent, xhat);
}

// Round 20
// 200.321 us; speedup vs baseline: 2.7010x; 2.5973x over previous
//
#include <hip/hip_runtime.h>
#include <hip/hip_bf16.h>

#define TQ_D   1024
#define TQ_KC  16
#define MERGE_K 512          // OpenBLAS KC-panel boundary (proven R9)
#define TQ_TOL  1.0e-3f      // >= 2x worst-case |y_mfma - y_ref| bound
#define LCAP    1024         // per-block LDS suspect-list capacity

typedef __attribute__((ext_vector_type(8))) short bf16x8;
typedef __attribute__((ext_vector_type(4))) float f32x4;

__device__ __forceinline__ unsigned short f2bf(float f) {
    union { __hip_bfloat16 h; unsigned short s; } u;
    u.h = __float2bfloat16(f);
    return u.s;
}
__device__ __forceinline__ float bf2f(unsigned short s) {
    union { unsigned int u; float f; } v;
    v.u = (unsigned int)s << 16;
    return v.f;
}

// ---------------------------------------------------------------------------
// K1-MFMA: y = x @ Pi^T via bf16 hi/lo 3-term split, f32 MFMA accum, literal
// f32 argmin. Suspects (dist < TOL) are aggregated in a per-block LDS list
// (LDS atomics), then ONE global atomicAdd per block reserves List space —
// fixes R19's 300us single-counter contention stall.
// ---------------------------------------------------------------------------
__global__ __launch_bounds__(256)
void tq_rq_mfma(const float* __restrict__ X,
                const float* __restrict__ Pi,
                const float* __restrict__ Cent,
                float* __restrict__ OutIdx,
                unsigned* __restrict__ Counter,
                unsigned* __restrict__ List,
                unsigned cap)
{
    __shared__ unsigned short Xh[128][40];
    __shared__ unsigned short Xl[128][40];
    __shared__ unsigned short Ph[128][40];
    __shared__ unsigned short Pl[128][40];
    __shared__ unsigned lcount;
    __shared__ unsigned gbase;
    __shared__ unsigned llist[LCAP];

    const int tid  = threadIdx.x;
    const int lane = tid & 63;
    const int wv   = tid >> 6;
    const int m0 = blockIdx.y * 128;
    const int n0 = blockIdx.x * 128;
    const int wr = (wv >> 1) * 64;
    const int wc = (wv & 1) * 64;
    const int l15 = lane & 15;
    const int k8  = (lane >> 4) * 8;

    const int srow = tid >> 1;
    const int scol = (tid & 1) * 16;

    const float* aP = X  + (size_t)(m0 + srow) * TQ_D + scol;
    const float* bP = Pi + (size_t)(n0 + srow) * TQ_D + scol;

    if (tid == 0) lcount = 0;

    f32x4 acc[4][4];
#pragma unroll
    for (int i = 0; i < 4; ++i)
#pragma unroll
        for (int j = 0; j < 4; ++j)
#pragma unroll
            for (int r = 0; r < 4; ++r) acc[i][j][r] = 0.0f;

    float4 va[4], vb[4];
#pragma unroll
    for (int q = 0; q < 4; ++q) {
        va[q] = *(const float4*)(aP + 4 * q);
        vb[q] = *(const float4*)(bP + 4 * q);
    }

#pragma unroll
    for (int q = 0; q < 4; ++q) {
        ushort4 ah, al, bh, bl;
        const float* fa = (const float*)&va[q];
        const float* fb = (const float*)&vb[q];
        ah.x = f2bf(fa[0]); al.x = f2bf(fa[0] - bf2f(ah.x));
        ah.y = f2bf(fa[1]); al.y = f2bf(fa[1] - bf2f(ah.y));
        ah.z = f2bf(fa[2]); al.z = f2bf(fa[2] - bf2f(ah.z));
        ah.w = f2bf(fa[3]); al.w = f2bf(fa[3] - bf2f(ah.w));
        bh.x = f2bf(fb[0]); bl.x = f2bf(fb[0] - bf2f(bh.x));
        bh.y = f2bf(fb[1]); bl.y = f2bf(fb[1] - bf2f(bh.y));
        bh.z = f2bf(fb[2]); bl.z = f2bf(fb[2] - bf2f(bh.z));
        bh.w = f2bf(fb[3]); bl.w = f2bf(fb[3] - bf2f(bh.w));
        *(ushort4*)&Xh[srow][scol + 4 * q] = ah;
        *(ushort4*)&Xl[srow][scol + 4 * q] = al;
        *(ushort4*)&Ph[srow][scol + 4 * q] = bh;
        *(ushort4*)&Pl[srow][scol + 4 * q] = bl;
    }
    __syncthreads();   // also covers lcount init

    for (int kt = 0; kt < 32; ++kt) {
        const bool more = (kt + 1) < 32;
        if (more) {
            const float* ap = aP + (kt + 1) * 32;
            const float* bp = bP + (kt + 1) * 32;
#pragma unroll
            for (int q = 0; q < 4; ++q) {
                va[q] = *(const float4*)(ap + 4 * q);
                vb[q] = *(const float4*)(bp + 4 * q);
            }
        }

        bf16x8 afh[4], afl[4], bfh[4], bfl[4];
#pragma unroll
        for (int i = 0; i < 4; ++i) {
            afh[i] = *(const bf16x8*)&Xh[wr + i * 16 + l15][k8];
            afl[i] = *(const bf16x8*)&Xl[wr + i * 16 + l15][k8];
        }
#pragma unroll
        for (int j = 0; j < 4; ++j) {
            bfh[j] = *(const bf16x8*)&Ph[wc + j * 16 + l15][k8];
            bfl[j] = *(const bf16x8*)&Pl[wc + j * 16 + l15][k8];
        }

#pragma unroll
        for (int i = 0; i < 4; ++i)
#pragma unroll
            for (int j = 0; j < 4; ++j) {
                acc[i][j] = __builtin_amdgcn_mfma_f32_16x16x32_bf16(
                    afh[i], bfh[j], acc[i][j], 0, 0, 0);
                acc[i][j] = __builtin_amdgcn_mfma_f32_16x16x32_bf16(
                    afl[i], bfh[j], acc[i][j], 0, 0, 0);
                acc[i][j] = __builtin_amdgcn_mfma_f32_16x16x32_bf16(
                    afh[i], bfl[j], acc[i][j], 0, 0, 0);
            }

        if (more) {
            __syncthreads();
#pragma unroll
            for (int q = 0; q < 4; ++q) {
                ushort4 ah, al, bh, bl;
                const float* fa = (const float*)&va[q];
                const float* fb = (const float*)&vb[q];
                ah.x = f2bf(fa[0]); al.x = f2bf(fa[0] - bf2f(ah.x));
                ah.y = f2bf(fa[1]); al.y = f2bf(fa[1] - bf2f(ah.y));
                ah.z = f2bf(fa[2]); al.z = f2bf(fa[2] - bf2f(ah.z));
                ah.w = f2bf(fa[3]); al.w = f2bf(fa[3] - bf2f(ah.w));
                bh.x = f2bf(fb[0]); bl.x = f2bf(fb[0] - bf2f(bh.x));
                bh.y = f2bf(fb[1]); bl.y = f2bf(fb[1] - bf2f(bh.y));
                bh.z = f2bf(fb[2]); bl.z = f2bf(fb[2] - bf2f(bh.z));
                bh.w = f2bf(fb[3]); bl.w = f2bf(fb[3] - bf2f(bh.w));
                *(ushort4*)&Xh[srow][scol + 4 * q] = ah;
                *(ushort4*)&Xl[srow][scol + 4 * q] = al;
                *(ushort4*)&Ph[srow][scol + 4 * q] = bh;
                *(ushort4*)&Pl[srow][scol + 4 * q] = bl;
            }
            __syncthreads();
        }
    }

    float c[TQ_KC];
#pragma unroll
    for (int q = 0; q < TQ_KC; ++q) c[q] = Cent[q];

#pragma unroll
    for (int i = 0; i < 4; ++i)
#pragma unroll
        for (int j = 0; j < 4; ++j)
#pragma unroll
            for (int r = 0; r < 4; ++r) {
                const int row = m0 + wr + i * 16 + (lane >> 4) * 4 + r;
                const int col = n0 + wc + j * 16 + l15;
                const float y = acc[i][j][r];
                int best = 0;
                float bd = fabsf(y - c[0]);
#pragma unroll
                for (int q = 1; q < TQ_KC; ++q) {
                    const float d = fabsf(y - c[q]);
                    if (d < bd) { bd = d; best = q; }
                }
                float dist = 1e30f;
#pragma unroll
                for (int q = 0; q < TQ_KC - 1; ++q) {
                    const float mid = 0.5f * (c[q] + c[q + 1]);
                    dist = fminf(dist, fabsf(y - mid));
                }
                if (dist < TQ_TOL) {
                    const unsigned id = ((unsigned)row << 10) | (unsigned)col;
                    const unsigned ls = atomicAdd(&lcount, 1u);   // LDS atomic
                    if (ls < LCAP) {
                        llist[ls] = id;
                    } else {                                      // overflow (rare)
                        const unsigned gs = atomicAdd(Counter, 1u);
                        if (gs < cap) List[gs] = id;
                    }
                }
                OutIdx[(size_t)row * TQ_D + col] = (float)best;
            }

    // one global atomic per block: reserve List space, copy LDS list out
    __syncthreads();
    if (tid == 0) {
        const unsigned cnt = min(lcount, (unsigned)LCAP);
        gbase = (cnt > 0) ? atomicAdd(Counter, cnt) : 0u;
    }
    __syncthreads();
    const unsigned cnt = min(lcount, (unsigned)LCAP);
    for (unsigned s = tid; s < cnt; s += 256) {
        const unsigned g = gbase + s;
        if (g < cap) List[g] = llist[s];
    }
}

// ---------------------------------------------------------------------------
// Fixup (compact, pipelined): one thread per suspect-list entry. EXACT
// reference realization: serial ascending-k f32 FMA chains within KC=512
// panels, one f32 merge add, literal f32 argmin. unroll-8 lets the compiler
// prefetch loads ahead of the dependent FMA chain (order unchanged).
// ---------------------------------------------------------------------------
__global__ __launch_bounds__(256)
void tq_fixup(const float* __restrict__ X,
              const float* __restrict__ Pi,
              const float* __restrict__ Cent,
              float* __restrict__ OutIdx,
              const unsigned* __restrict__ Counter,
              const unsigned* __restrict__ List,
              unsigned cap)
{
    const unsigned count = min(*Counter, cap);
    for (unsigned s = blockIdx.x * 256 + threadIdx.x; s < count;
         s += gridDim.x * 256) {
        const unsigned id = List[s];
        const int m = id >> 10;
        const int n = id & (TQ_D - 1);
        const float* xr = X  + (size_t)m * TQ_D;
        const float* pr = Pi + (size_t)n * TQ_D;

        float a1 = 0.0f, a2 = 0.0f;
#pragma unroll 8
        for (int k = 0; k < MERGE_K; k += 4) {
            const float4 xa = *(const float4*)(xr + k);
            const float4 pa = *(const float4*)(pr + k);
            a1 = fmaf(xa.x, pa.x, a1);
            a1 = fmaf(xa.y, pa.y, a1);
            a1 = fmaf(xa.z, pa.z, a1);
            a1 = fmaf(xa.w, pa.w, a1);
        }
#pragma unroll 8
        for (int k = MERGE_K; k < TQ_D; k += 4) {
            const float4 xa = *(const float4*)(xr + k);
            const float4 pa = *(const float4*)(pr + k);
            a2 = fmaf(xa.x, pa.x, a2);
            a2 = fmaf(xa.y, pa.y, a2);
            a2 = fmaf(xa.z, pa.z, a2);
            a2 = fmaf(xa.w, pa.w, a2);
        }
        const float y = a1 + a2;   // exact R9 panel merge

        float c[TQ_KC];
#pragma unroll
        for (int q = 0; q < TQ_KC; ++q) c[q] = Cent[q];
        int best = 0;
        float bd = fabsf(y - c[0]);
#pragma unroll
        for (int q = 1; q < TQ_KC; ++q) {
            const float d = fabsf(y - c[q]);
            if (d < bd) { bd = d; best = q; }
        }
        OutIdx[(size_t)m * TQ_D + n] = (float)best;
    }
}

// ---------------------------------------------------------------------------
// Kernel 2 (MFMA, proven R15): x_hat = dequant(idx) @ Pi, bf16 MFMA f32-acc.
// Overwrites the counter/list scratch (xhat region) with the real output.
// ---------------------------------------------------------------------------
__global__ __launch_bounds__(256)
void tq_dq_mfma(const float* __restrict__ IdxF,
                const float* __restrict__ Pi,
                const float* __restrict__ Cent,
                float* __restrict__ Xhat)
{
    __shared__ unsigned short Ys[128][40];
    __shared__ unsigned short Ps[128][40];
    __shared__ unsigned short csb[TQ_KC];

    const int tid  = threadIdx.x;
    const int lane = tid & 63;
    const int wv   = tid >> 6;
    const int m0 = blockIdx.y * 128;
    const int n0 = blockIdx.x * 128;
    const int wr = (wv >> 1) * 64;
    const int wc = (wv & 1) * 64;
    const int l15 = lane & 15;
    const int k8  = (lane >> 4) * 8;

    const int arow = tid >> 1;
    const int acol = (tid & 1) * 16;
    const int bn   = tid & 127;
    const int bkq  = (tid >> 7) * 16;

    const float* aP = IdxF + (size_t)(m0 + arow) * TQ_D + acol;
    const float* bP = Pi + (size_t)bkq * TQ_D + n0 + bn;

    if (tid < TQ_KC) csb[tid] = f2bf(Cent[tid]);

    f32x4 acc[4][4];
#pragma unroll
    for (int i = 0; i < 4; ++i)
#pragma unroll
        for (int j = 0; j < 4; ++j)
#pragma unroll
            for (int r = 0; r < 4; ++r) acc[i][j][r] = 0.0f;

    float4 va[4];
    float  vb[16];
#pragma unroll
    for (int q = 0; q < 4; ++q) va[q] = *(const float4*)(aP + 4 * q);
#pragma unroll
    for (int k = 0; k < 16; ++k) vb[k] = bP[(size_t)k * TQ_D];

    __syncthreads();   // csb ready

#pragma unroll
    for (int q = 0; q < 4; ++q) {
        ushort4 w;
        w.x = csb[(int)va[q].x & 15];
        w.y = csb[(int)va[q].y & 15];
        w.z = csb[(int)va[q].z & 15];
        w.w = csb[(int)va[q].w & 15];
        *(ushort4*)&Ys[arow][acol + 4 * q] = w;
    }
#pragma unroll
    for (int k = 0; k < 16; ++k) Ps[bn][bkq + k] = f2bf(vb[k]);
    __syncthreads();

    for (int kt = 0; kt < 32; ++kt) {
        const bool more = (kt + 1) < 32;
        if (more) {
            const float* ap = aP + (kt + 1) * 32;
            const float* bp = bP + (size_t)(kt + 1) * 32 * TQ_D;
#pragma unroll
            for (int q = 0; q < 4; ++q) va[q] = *(const float4*)(ap + 4 * q);
#pragma unroll
            for (int k = 0; k < 16; ++k) vb[k] = bp[(size_t)k * TQ_D];
        }

        bf16x8 af[4], bfr[4];
#pragma unroll
        for (int i = 0; i < 4; ++i)
            af[i] = *(const bf16x8*)&Ys[wr + i * 16 + l15][k8];
#pragma unroll
        for (int j = 0; j < 4; ++j)
            bfr[j] = *(const bf16x8*)&Ps[wc + j * 16 + l15][k8];

#pragma unroll
        for (int i = 0; i < 4; ++i)
#pragma unroll
            for (int j = 0; j < 4; ++j)
                acc[i][j] = __builtin_amdgcn_mfma_f32_16x16x32_bf16(
                    af[i], bfr[j], acc[i][j], 0, 0, 0);

        if (more) {
            __syncthreads();
#pragma unroll
            for (int q = 0; q < 4; ++q) {
                ushort4 w;
                w.x = csb[(int)va[q].x & 15];
                w.y = csb[(int)va[q].y & 15];
                w.z = csb[(int)va[q].z & 15];
                w.w = csb[(int)va[q].w & 15];
                *(ushort4*)&Ys[arow][acol + 4 * q] = w;
            }
#pragma unroll
            for (int k = 0; k < 16; ++k) Ps[bn][bkq + k] = f2bf(vb[k]);
            __syncthreads();
        }
    }

#pragma unroll
    for (int i = 0; i < 4; ++i)
#pragma unroll
        for (int j = 0; j < 4; ++j)
#pragma unroll
            for (int r = 0; r < 4; ++r) {
                const int row = wr + i * 16 + (lane >> 4) * 4 + r;
                const int col = wc + j * 16 + l15;
                Xhat[(size_t)(m0 + row) * TQ_D + n0 + col] = acc[i][j][r];
            }
}

// ---------------------------------------------------------------------------
extern "C" void kernel_launch(void* const* d_in, const int* in_sizes, int n_in,
                              void* d_out, int out_size, void* d_ws, size_t ws_size,
                              hipStream_t stream)
{
    const float* x    = (const float*)d_in[0];   // [N, 1024]
    const float* Pi   = (const float*)d_in[1];   // [1024, 1024]
    const float* cent = (const float*)d_in[2];   // [16]
    float* out = (float*)d_out;

    const int ND = in_sizes[0];      // N * 1024
    const int N  = ND / TQ_D;        // 4096

    float* xhat = out;               // output 0 (scratch: counter+list pre-K2)
    float* oidx = out + ND;          // output 1: indices as float

    unsigned* counter = (unsigned*)xhat;
    unsigned* list    = (unsigned*)xhat + 16;
    const unsigned cap = (unsigned)(ND - 16);

    hipMemsetAsync(counter, 0, 4, stream);   // zero suspect counter

    dim3 grid(TQ_D / 128, N / 128);  // (8, 32) = 256 blocks

    // Pass 1: MFMA hi/lo rotate+quantize -> indices + block-aggregated suspects.
    tq_rq_mfma<<<grid, 256, 0, stream>>>(x, Pi, cent, oidx, counter, list, cap);

    // Pass 2: dense exact recompute of suspects (R9 realization).
    tq_fixup<<<256, 256, 0, stream>>>(x, Pi, cent, oidx, counter, list, cap);

    // Pass 3: dequant + unrotate (MFMA) -> xhat (overwrites scratch).
    tq_dq_mfma<<<grid, 256, 0, stream>>>(oidx, Pi, cent, xhat);
}